// Round 1
// 1396.215 us; speedup vs baseline: 7.2318x; 7.2318x over previous
//
#include <hip/hip_runtime.h>
#include <cstdint>
#include <cstddef>

// Problem constants: B=4,S=2048 -> N=8192; I=K=4096; O=11008; G=128
#define N_ 8192
#define K_ 4096
#define O_ 11008

typedef __bf16 bf16x8 __attribute__((ext_vector_type(8)));
typedef float f32x4 __attribute__((ext_vector_type(4)));

__device__ __forceinline__ uint16_t f2bf(float f) {
    // round-to-nearest-even fp32 -> bf16 (finite inputs)
    uint32_t u = __float_as_uint(f);
    u += 0x7fffu + ((u >> 16) & 1u);
    return (uint16_t)(u >> 16);
}
__device__ __forceinline__ float bf2f(uint16_t b) {
    return __uint_as_float(((uint32_t)b) << 16);
}
__device__ __forceinline__ float bfr(float f) { return bf2f(f2bf(f)); }

// async global(16B/lane) -> LDS (wave-uniform base + lane*16, linear)
__device__ __forceinline__ void async_cp16(const uint16_t* gsrc, uint16_t* ldst) {
    __builtin_amdgcn_global_load_lds(
        (__attribute__((address_space(1))) void*)gsrc,
        (__attribute__((address_space(3))) void*)ldst, 16, 0, 0);
}

// ---------------- pass 1: X fp32 -> bf16 ----------------
__global__ __launch_bounds__(256) void xcast(const float* __restrict__ X,
                                             uint16_t* __restrict__ Xb) {
    const size_t n8 = (size_t)N_ * K_ / 8;
    size_t i = (size_t)blockIdx.x * 256u + threadIdx.x;
    const size_t stride = (size_t)gridDim.x * 256u;
    for (; i < n8; i += stride) {
        const float4* p = (const float4*)(X + i * 8);
        float4 a = p[0], b = p[1];
        union { uint16_t u[8]; uint4 v; } r;
        r.u[0] = f2bf(a.x); r.u[1] = f2bf(a.y); r.u[2] = f2bf(a.z); r.u[3] = f2bf(a.w);
        r.u[4] = f2bf(b.x); r.u[5] = f2bf(b.y); r.u[6] = f2bf(b.z); r.u[7] = f2bf(b.w);
        *(uint4*)(Xb + i * 8) = r.v;
    }
}

// ---------------- pass 2: dequant int32-codes -> bf16 W ----------------
// w = bf16( bf16((q-8)*s) + z ), matching the reference's bf16 elementwise chain.
__global__ __launch_bounds__(256) void wdeq(const int* __restrict__ Q,
                                            const float* __restrict__ SZ,
                                            uint16_t* __restrict__ Wb) {
    const size_t n8 = (size_t)O_ * K_ / 8;
    size_t i = (size_t)blockIdx.x * 256u + threadIdx.x;
    const size_t stride = (size_t)gridDim.x * 256u;
    for (; i < n8; i += stride) {
        const size_t e = i * 8;
        const size_t o = e >> 12;                 // / K_ (4096)
        const uint32_t k = (uint32_t)(e & (K_ - 1));
        const uint32_t g = k >> 7;                // /128 group
        const float2 sz = *(const float2*)(SZ + 2 * ((size_t)g * O_ + o));
        const float s = bfr(sz.x);                // safety no-op on bf16-upcast fp32
        const float z = bfr(sz.y);
        const int4* qp = (const int4*)(Q + e);
        int4 qa = qp[0], qb = qp[1];
        int qs[8] = {qa.x, qa.y, qa.z, qa.w, qb.x, qb.y, qb.z, qb.w};
        union { uint16_t u[8]; uint4 v; } r;
#pragma unroll
        for (int j = 0; j < 8; ++j) {
            float w1 = bfr((float)(qs[j] - 8) * s);
            r.u[j] = f2bf(w1 + z);
        }
        *(uint4*)(Wb + e) = r.v;
    }
}

// ---------------- pass 3: bf16 MFMA GEMM (m97 structure) ----------------
// C[n][o] = sum_k A[n][k]*B[o][k]; 128x128 tile, BK=32, 4 waves, each wave owns
// a 64x64 quadrant as 4x4 frags of 16x16. global_load_lds width-16 staging.
__global__ __launch_bounds__(256) void gemm_mfma(const uint16_t* __restrict__ A,
                                                 const uint16_t* __restrict__ B,
                                                 float* __restrict__ C) {
    __shared__ uint16_t As[128 * 32];   // [row][k] linear, 64B rows
    __shared__ uint16_t Bs[128 * 32];

    const int tid = threadIdx.x;
    const int l = tid & 63;
    const int w = tid >> 6;            // wave 0..3
    const int wr = w >> 1;             // quadrant row 0..1
    const int wc = w & 1;              // quadrant col 0..1
    const int n0 = blockIdx.x * 128;   // 64 tiles
    const int o0 = blockIdx.y * 128;   // 86 tiles

    // staging map: wave w copies tile-rows [w*16, w*16+16) and [64+w*16, ...)
    // lane l -> row (base + l/4), k elems (l&3)*8  (16B per lane, linear in LDS)
    const int srow = l >> 2;
    const int skq = (l & 3) * 8;
    const uint16_t* pA0 = A + (size_t)(n0 + w * 16 + srow) * K_ + skq;
    const uint16_t* pA1 = pA0 + (size_t)64 * K_;
    const uint16_t* pB0 = B + (size_t)(o0 + w * 16 + srow) * K_ + skq;
    const uint16_t* pB1 = pB0 + (size_t)64 * K_;
    uint16_t* ldsA0 = &As[(w * 16) * 32];
    uint16_t* ldsA1 = &As[(64 + w * 16) * 32];
    uint16_t* ldsB0 = &Bs[(w * 16) * 32];
    uint16_t* ldsB1 = &Bs[(64 + w * 16) * 32];

    f32x4 acc[4][4] = {};

    const int lr = l & 15;             // frag row / C col
    const int lk = (l >> 4) * 8;       // frag k offset

    for (int k0 = 0; k0 < K_; k0 += 32) {
        async_cp16(pA0 + k0, ldsA0);
        async_cp16(pA1 + k0, ldsA1);
        async_cp16(pB0 + k0, ldsB0);
        async_cp16(pB1 + k0, ldsB1);
        __syncthreads();   // compiler emits vmcnt(0) drain before barrier

        bf16x8 af[4], bv[4];
#pragma unroll
        for (int m = 0; m < 4; ++m)
            af[m] = *(const bf16x8*)&As[(wr * 64 + m * 16 + lr) * 32 + lk];
#pragma unroll
        for (int n = 0; n < 4; ++n)
            bv[n] = *(const bf16x8*)&Bs[(wc * 64 + n * 16 + lr) * 32 + lk];
#pragma unroll
        for (int m = 0; m < 4; ++m)
#pragma unroll
            for (int n = 0; n < 4; ++n)
                acc[m][n] = __builtin_amdgcn_mfma_f32_16x16x32_bf16(af[m], bv[n], acc[m][n], 0, 0, 0);
        __syncthreads();   // protect LDS before next-iter restage
    }

    // C/D layout (m89-verified): col = lane&15, row = (lane>>4)*4 + reg
    const int rbase = (l >> 4) * 4;
#pragma unroll
    for (int m = 0; m < 4; ++m) {
#pragma unroll
        for (int n = 0; n < 4; ++n) {
#pragma unroll
            for (int r = 0; r < 4; ++r) {
                const size_t row = (size_t)(n0 + wr * 64 + m * 16 + rbase + r);
                C[row * O_ + (o0 + wc * 64 + n * 16 + lr)] = bfr(acc[m][n][r]);
            }
        }
    }
}

// ---------------- fallback: verified fp32 VALU kernel (previous session) ----------------
__global__ __launch_bounds__(256) void gemm_probe_f32sz(const float* __restrict__ X,
                                                        const int* __restrict__ Q,
                                                        const float* __restrict__ SZf,
                                                        float* __restrict__ C) {
    __shared__ float xs[32][64];   // [k][n]
    __shared__ float ws[32][64];   // [k][o]
    const int tid = threadIdx.x;
    const int n0 = blockIdx.x * 64;
    const int o0 = blockIdx.y * 64;
    const int tn = tid >> 4;
    const int to = tid & 15;

    const int srow = tid >> 2;
    const int skq = (tid & 3) * 8;

    float acc[4][4] = {};

    for (int k0 = 0; k0 < K_; k0 += 32) {
        {
            const float4* xp = (const float4*)(X + (size_t)(n0 + srow) * K_ + k0 + skq);
            float4 a = xp[0], b = xp[1];
            float v[8] = {a.x, a.y, a.z, a.w, b.x, b.y, b.z, b.w};
#pragma unroll
            for (int j = 0; j < 8; ++j) xs[skq + j][srow] = bfr(v[j]);
        }
        {
            const int o = o0 + srow;
            const uint32_t g = (uint32_t)k0 >> 7;
            const size_t p = (size_t)g * O_ + o;
            const float s = bfr(SZf[2 * p]);
            const float z = bfr(SZf[2 * p + 1]);
            const int4* qp = (const int4*)(Q + (size_t)o * K_ + k0 + skq);
            int4 qa = qp[0], qb = qp[1];
            int qs[8] = {qa.x, qa.y, qa.z, qa.w, qb.x, qb.y, qb.z, qb.w};
#pragma unroll
            for (int j = 0; j < 8; ++j) {
                float w1 = bfr((float)(qs[j] - 8) * s);
                ws[skq + j][srow] = bfr(w1 + z);
            }
        }
        __syncthreads();

#pragma unroll 8
        for (int kk = 0; kk < 32; ++kk) {
            const float4 xv = *(const float4*)&xs[kk][tn * 4];
            const float4 wv = *(const float4*)&ws[kk][to * 4];
            const float xa[4] = {xv.x, xv.y, xv.z, xv.w};
            const float wa[4] = {wv.x, wv.y, wv.z, wv.w};
#pragma unroll
            for (int i = 0; i < 4; ++i)
#pragma unroll
                for (int j = 0; j < 4; ++j)
                    acc[i][j] = fmaf(xa[i], wa[j], acc[i][j]);
        }
        __syncthreads();
    }

#pragma unroll
    for (int i = 0; i < 4; ++i) {
        const size_t row = (size_t)(n0 + tn * 4 + i);
#pragma unroll
        for (int j = 0; j < 4; ++j) {
            C[row * O_ + (o0 + to * 4 + j)] = bfr(acc[i][j]);
        }
    }
}

__global__ __launch_bounds__(256) void sentinel_fill(float* __restrict__ C, size_t n, float v) {
    size_t i = (size_t)blockIdx.x * 256u + threadIdx.x;
    size_t stride = (size_t)gridDim.x * 256u;
    for (; i < n; i += stride) C[i] = v;
}

extern "C" void kernel_launch(void* const* d_in, const int* in_sizes, int n_in,
                              void* d_out, int out_size, void* d_ws, size_t ws_size,
                              hipStream_t stream) {
    const float* x = (const float*)d_in[0];
    const int* q = (const int*)d_in[1];
    const float* szf = (const float*)d_in[2];
    float* out = (float*)d_out;

    // Host-side contract checks -> distinct absmax signatures if violated.
    float sentinel = 0.0f;
    if (n_in < 3)                         sentinel = 1000.0f;
    else if (in_sizes[0] != 33554432)     sentinel = 2000.0f;  // x: 8192*4096
    else if (in_sizes[1] != 45088768)     sentinel = 3000.0f;  // weight_q: 11008*4096
    else if (in_sizes[2] != 704512)       sentinel = 4000.0f;  // s&z: 32*11008*2
    else if (out_size   != 90177536)      sentinel = 5000.0f;  // 8192*11008

    if (sentinel != 0.0f) {
        sentinel_fill<<<8192, 256, 0, stream>>>(out, (size_t)out_size, sentinel);
        return;
    }

    const size_t xb_bytes = (size_t)N_ * K_ * 2;   // 67,108,864
    const size_t wb_bytes = (size_t)O_ * K_ * 2;   // 90,177,536

    if (ws_size >= xb_bytes + wb_bytes) {
        uint16_t* Xb = (uint16_t*)d_ws;
        uint16_t* Wb = (uint16_t*)((char*)d_ws + xb_bytes);
        xcast<<<2048, 256, 0, stream>>>(x, Xb);
        wdeq<<<2048, 256, 0, stream>>>(q, szf, Wb);
        dim3 grid(N_ / 128, O_ / 128);   // 64 x 86
        gemm_mfma<<<grid, 256, 0, stream>>>(Xb, Wb, out);
    } else {
        // workspace too small: verified fp32 VALU fallback
        dim3 grid(N_ / 64, O_ / 64);     // 128 x 172
        gemm_probe_f32sz<<<grid, 256, 0, stream>>>(x, q, szf, out);
    }
}